// Round 14
// baseline (277.957 us; speedup 1.0000x reference)
//
#include <hip/hip_runtime.h>
#include <hip/hip_bf16.h>

// B=4, N=256, F=64, H=256, A=16, T=3.  BN=1024 rows.
// bf16 inputs (runtime-verified); adjacency int32.
// GEMMs: bf16 MFMA 16x16x32. Weights EXACT in bf16.
// Activations as split hi/lo bf16 pairs along K; weights duplicated along K.
// R1-R9: fusion + K-dedup + LDS pad + 256-blk gigru: 265us.
// R10 gh-fusion; R11 XCD affinity (257.6 best); R12 interleave; R13 footprint
// cut (FETCH 6.5->5.8MB) -- gigru TIME INVARIANT ~44-49us through all 8
// structural theories. Last untested axis: all variants ran 1 block/CU,
// 1 wave/SIMD (Occ 4.5%) -- a stalled wave leaves the SIMD empty.
// R14: co-resident TLP. gigru 512 blocks (8-row slabs, 2 blocks/CU;
// rows 8..15 of the 16-row M-frag are dead lanes, outputs unwritten ->
// bitwise identical). hcat 256 blocks (16-row tiles). Same XCD maps.

typedef unsigned short ushort_t;
typedef short bf8_t __attribute__((ext_vector_type(8)));
typedef float f4_t  __attribute__((ext_vector_type(4)));

#define BN_ROWS 1024

// ---- bf16 regions (USHORT offsets) ----
#define UB_NFB    0         // 65536   NF [1024][64] (exact)
#define UB_PW1T   65536     // 16384   preW1^T [256][64]
#define UB_PW2T   81920     // 65536   preW2^T [256][256]
#define UB_WCATT  147456    // 327680  Wcat^T [1280][256] (dedup: k&255)
#define UB_WGT    475136    // 442368  Wg^T [768][576] = [hi(288)|lo(288)]
#define UB_H2     917504    // 524288  h buf A [1024][512] hi|lo
#define UB_EHAT2  1441792   // 589824  Ehat [1024][576] = [Eh(288)|El(288)]
// ushort end 2031616 = float 1015808

// ---- fp32 regions (FLOAT offsets) ----
#define F_PREB1   1015808   // 256
#define F_PREB2   1016064   // 256
#define F_BCAT    1016320   // 1280  [msg_b1 | 0 | gru_bhh]
#define F_BIH     1017600   // 768
#define F_ROW1    1018368   // 65536
#define F_ROB1    1083904   // 256
#define F_ROW2    1084160   // 4096
#define F_ROB2    1088256   // 16
// old F_H region [1088272, 1350416) reused:
#define EJ_U      2176544   // ushort offset (= 1088272*2): ej [1024][256] ushort
#define F_ECNT    1219344   // 1024 ints: per-row edge counts
#define F_HCAT    1350416   // 524288 [hi_p | hj] fp32
// gap [1874704, 2661136) floats reused:
#define UB_H2B    3749408   // ushort offset (= 1874704*2): h buf B [1024][512]
#define F_FLAG    2661136   // 1 int
#define F_GCNT    2661140   // 4 ints: per-graph readout arrival counters

// ---- convert index space ----
#define CVa 65536     // end NFB
#define CVb 81920     // end PW1T
#define CVc 147456    // end PW2T
#define CVd 475136    // end WCATT (1280*256)
#define CV_TOTAL 547600   // + 72464 fp32 tail
#define NCONV 1070        // convert blocks; then 216 wg blocks; then 64 compact

__device__ __forceinline__ float bf2f(ushort_t u) {
    return __uint_as_float(((unsigned int)u) << 16);
}
__device__ __forceinline__ ushort_t f2b(float v) {
    __hip_bfloat16 b = __float2bfloat16(v);
    return *reinterpret_cast<ushort_t*>(&b);
}
__device__ __forceinline__ float relu(float v) { return v < 0.f ? 0.f : v; }  // NaN-propagating
__device__ __forceinline__ float ld(const void* p, int i, int isf32) {
    return isf32 ? ((const float*)p)[i] : bf2f(((const ushort_t*)p)[i]);
}

// detect + convert [0,NCONV) + wg [NCONV,NCONV+216) + adj-compact [+216,+280).
__global__ __launch_bounds__(256) void convwg_kernel(
    const void* nf, const void* preW1, const void* preb1, const void* preW2, const void* preb2,
    const void* msgW1, const void* msgb1, const void* msgW2, const void* msgb2,
    const void* gruWih, const void* gruWhh, const void* grubih, const void* grubhh,
    const void* roW1, const void* rob1, const void* roW2, const void* rob2,
    const int* __restrict__ adj, float* __restrict__ w)
{
    __shared__ float w2s[4 * 256];
    __shared__ int cnt;
    __shared__ int cnt2;
    const int t = threadIdx.x;
    ushort_t* wb = (ushort_t*)w;

    // ---- inline detect (redundant per block; 4KB L2-hit scan) ----
    if (t == 0) cnt = 0;
    __syncthreads();
    {
        const ushort_t* nf0 = (const ushort_t*)nf;
        int bad = 0;
        for (int i = 0; i < 8; ++i) {
            ushort_t u = nf0[(t * 8 + i) * 2];
            int ex = (u >> 7) & 0xFF;
            if ((u & 0x7fff) != 0 && (ex < 100 || ex > 140)) bad++;
        }
        atomicAdd(&cnt, bad);
    }
    __syncthreads();
    const int f32 = (cnt > 512) ? 1 : 0;

    if (blockIdx.x == 0) {          // publish flag + zero readout counters
        if (t < 4) ((int*)(w + F_GCNT))[t] = 0;
        if (t == 4) *(int*)(w + F_FLAG) = f32;
    }

    if (blockIdx.x < NCONV) {
        const int e0 = (blockIdx.x * 256 + t) * 2;
#pragma unroll
        for (int u2 = 0; u2 < 2; ++u2) {
            int e = e0 + u2;
            if (e >= CV_TOTAL) break;
            if (e < CVa) {                                    // NF
                wb[UB_NFB + e] = f2b(ld(nf, e, f32));
            } else if (e < CVb) {                             // preW1^T [256][64]
                int i = e - CVa; int n = i >> 6, k = i & 63;
                wb[UB_PW1T + i] = f2b(ld(preW1, k * 256 + n, f32));
            } else if (e < CVc) {                             // preW2^T [256][256]
                int i = e - CVb; int n = i >> 8, k = i & 255;
                wb[UB_PW2T + i] = f2b(ld(preW2, k * 256 + n, f32));
            } else if (e < CVd) {                             // Wcat^T [1280][256]
                int i = e - CVc; int n = i >> 8, k = i & 255;
                float v;
                if (n < 256)      v = ld(msgW1, k * 256 + n, f32);
                else if (n < 512) v = ld(msgW1, (256 + k) * 256 + (n - 256), f32);
                else              v = ld(gruWhh, k * 768 + (n - 512), f32);
                wb[UB_WCATT + i] = f2b(v);
            } else {                                          // fp32 tail
                int f = e - CVd;
                float v;
                if (f < 256)        v = ld(preb1, f, f32);
                else if (f < 512)   v = ld(preb2, f - 256, f32);
                else if (f < 1792) {
                    int c = f - 512;
                    if (c < 256)      v = ld(msgb1, c, f32);
                    else if (c < 512) v = 0.f;
                    else              v = ld(grubhh, c - 512, f32);
                }
                else if (f < 2560)  v = ld(grubih, f - 1792, f32);
                else if (f < 68096) v = ld(roW1, f - 2560, f32);
                else if (f < 68352) v = ld(rob1, f - 68096, f32);
                else if (f < 72448) v = ld(roW2, f - 68352, f32);
                else                v = ld(rob2, f - 72448, f32);
                w[F_PREB1 + f] = v;
            }
        }
        return;
    }

    if (blockIdx.x < NCONV + 216) {
        // ---- wg path: Wg[k][p] = sum_n W2hat[k][n]*Wih[n][p] -> WgT[p][576] ----
        const int wt = blockIdx.x - NCONV;   // [0,216)
        const int p0 = (wt % 3) * 256;
        const int k0 = (wt / 3) * 4;
        for (int i = t; i < 4 * 256; i += 256) {
            int r = i >> 8, n = i & 255;
            int krow = k0 + r;
            float v;
            if (krow < 256)       v = ld(msgW2, krow * 256 + n, f32);
            else if (krow == 256) v = ld(msgb2, n, f32);
            else                  v = 0.f;
            w2s[i] = v;
        }
        __syncthreads();
        const int p = p0 + t;
        float acc4[4] = {};
        for (int n0 = 0; n0 < 256; n0 += 32) {
            float wv[32];
#pragma unroll
            for (int i = 0; i < 32; ++i)
                wv[i] = ld(gruWih, (n0 + i) * 768 + p, f32);
#pragma unroll
            for (int r = 0; r < 4; ++r) {
                float acc = acc4[r];
#pragma unroll
                for (int q = 0; q < 8; ++q) {
                    f4_t w4 = *(const f4_t*)&w2s[r * 256 + n0 + q * 4];
                    acc += w4[0] * wv[q * 4 + 0] + w4[1] * wv[q * 4 + 1]
                         + w4[2] * wv[q * 4 + 2] + w4[3] * wv[q * 4 + 3];
                }
                acc4[r] = acc;
            }
        }
#pragma unroll
        for (int r = 0; r < 4; ++r) {
            int krow = k0 + r;
            ushort_t hi = f2b(acc4[r]);
            ushort_t lo = f2b(acc4[r] - bf2f(hi));
            wb[UB_WGT + p * 576 + krow] = hi;
            wb[UB_WGT + p * 576 + 288 + krow] = lo;
        }
        return;
    }

    // ---- adjacency compaction: 64 blocks x 16 rows -> ej lists + counts ----
    {
        const int r0 = (blockIdx.x - (NCONV + 216)) * 16;
        for (int i = 0; i < 16; ++i) {
            const int row = r0 + i;
            __syncthreads();
            if (t == 0) cnt2 = 0;
            __syncthreads();
            if (adj[row * 256 + t]) {
                int p = atomicAdd(&cnt2, 1);
                wb[EJ_U + row * 256 + p] = (ushort_t)t;
            }
            __syncthreads();
            if (t == 0) ((int*)(w + F_ECNT))[row] = cnt2;
        }
    }
}

// Fused pre-net: X = relu(NF@preW1+b1) (in LDS), h = X@preW2+b2 -> H2 (buf A).
// 32 blocks x 32 rows, XCD-pinned: graph g on XCDs {2g,2g+1}.
__global__ __launch_bounds__(256) void prenet_kernel(float* __restrict__ w)
{
    __shared__ ushort_t As[32 * 64];    // NF tile      4KB
    __shared__ ushort_t Xs[32 * 256];   // X tile      16KB
    __shared__ ushort_t Bs[256 * 32];   // weight slab 16KB
    ushort_t* wb = (ushort_t*)w;
    const int t = threadIdx.x;
    const int wave = t >> 6, lane = t & 63;
    const int ln = lane & 15, quad = lane >> 4;
    const int wr = (wave & 1) * 16, wc = (wave >> 1) * 128;
    const int xcd = blockIdx.x & 7;
    const int gph = xcd >> 1;
    const int lidx = ((blockIdx.x >> 3) << 1) | (xcd & 1);   // 0..7
    const int rbase = gph * 256 + lidx * 32;
    const int srow = t >> 2, skc = (t & 3) << 3;

    // stage NF tile [32][64]: 1 bf8 per thread
    {
        int row = t >> 3, kc = (t & 7) << 3;
        *(bf8_t*)(&As[row * 64 + kc]) =
            *(const bf8_t*)(&wb[UB_NFB + (rbase + row) * 64 + kc]);
    }

    f4_t acc[8] = {};
    // phase A: X = relu(NF @ PW1T + b1), K=64
    for (int k0 = 0; k0 < 64; k0 += 32) {
        __syncthreads();
#pragma unroll
        for (int rr = 0; rr < 4; ++rr) {
            int n = srow + 64 * rr;
            *(bf8_t*)(&Bs[n * 32 + skc]) =
                *(const bf8_t*)(&wb[UB_PW1T + n * 64 + k0 + skc]);
        }
        __syncthreads();
        bf8_t af = *(const bf8_t*)(&As[(wr + ln) * 64 + k0 + quad * 8]);
#pragma unroll
        for (int n = 0; n < 8; ++n) {
            bf8_t bfr = *(const bf8_t*)(&Bs[(wc + n * 16 + ln) * 32 + quad * 8]);
            acc[n] = __builtin_amdgcn_mfma_f32_16x16x32_bf16(af, bfr, acc[n], 0, 0, 0);
        }
    }
    __syncthreads();
#pragma unroll
    for (int n = 0; n < 8; ++n) {
        int col = wc + n * 16 + ln;
        float bb = w[F_PREB1 + col];
#pragma unroll
        for (int r = 0; r < 4; ++r) {
            int row = wr + quad * 4 + r;
            Xs[row * 256 + col] = f2b(relu(acc[n][r] + bb));
        }
        acc[n] = (f4_t){0.f, 0.f, 0.f, 0.f};
    }
    __syncthreads();

    // phase B: h = X @ PW2T + b2, K=256
    for (int k0 = 0; k0 < 256; k0 += 32) {
        __syncthreads();
#pragma unroll
        for (int rr = 0; rr < 4; ++rr) {
            int n = srow + 64 * rr;
            *(bf8_t*)(&Bs[n * 32 + skc]) =
                *(const bf8_t*)(&wb[UB_PW2T + n * 256 + k0 + skc]);
        }
        __syncthreads();
        bf8_t af = *(const bf8_t*)(&Xs[(wr + ln) * 256 + k0 + quad * 8]);
#pragma unroll
        for (int n = 0; n < 8; ++n) {
            bf8_t bfr = *(const bf8_t*)(&Bs[(wc + n * 16 + ln) * 32 + quad * 8]);
            acc[n] = __builtin_amdgcn_mfma_f32_16x16x32_bf16(af, bfr, acc[n], 0, 0, 0);
        }
    }
#pragma unroll
    for (int n = 0; n < 8; ++n) {
        int col = wc + n * 16 + ln;
        float bb = w[F_PREB2 + col];
#pragma unroll
        for (int r = 0; r < 4; ++r) {
            int grow = rbase + wr + quad * 4 + r;
            float v = acc[n][r] + bb;
            ushort_t hi = f2b(v);
            wb[UB_H2 + grow * 512 + col] = hi;
            wb[UB_H2 + grow * 512 + 256 + col] = f2b(v - bf2f(hi));
        }
    }
}

// hcat GEMM: C[1024,512] = h[1024,512] @ WcatT[0..512]^T + bias ([hi_p|hj]).
// R14: 16x128 tiles, 256 blocks (2 blocks/CU), XCD-pinned. BK=64, LDS
// stride 104u, reg-prefetch 1. Wave = 16 rows x 32 cols (2 n-frags).
#define HLD 104
__global__ __launch_bounds__(256) void hcat_kernel(float* __restrict__ w, int hoff)
{
    __shared__ ushort_t As[16 * HLD];    // 3.3KB
    __shared__ ushort_t Bs[128 * HLD];   // 26.6KB
    ushort_t* wb = (ushort_t*)w;
    const ushort_t* A  = wb + hoff;
    const ushort_t* Bt = wb + UB_WCATT;
    const int t = threadIdx.x;
    const int wave = t >> 6, lane = t & 63;
    const int ln = lane & 15, quad = lane >> 4;
    const int xcd = blockIdx.x & 7;
    const int gph = xcd >> 1;
    const int lidx = ((blockIdx.x >> 3) << 1) | (xcd & 1);   // 0..63
    const int bm = gph * 256 + (lidx >> 2) * 16;
    const int bn = (lidx & 3) * 128;
    const int wn = wave * 32;

    // staging: A 16 rows x 64u = 128 chunks (t<128); B 128x64u (4/thread)
    const int aval = (t < 128);
    const int arow = t >> 3, akc = (t & 7) << 3;
    const int agoff = (bm + arow) * 512 + akc;
    const int aloff = arow * HLD + akc;
    int bgoff[4], bloff[4];
#pragma unroll
    for (int i = 0; i < 4; ++i) {
        int slot = i * 256 + t;
        int brow = slot >> 3, bkc = (slot & 7) << 3;
        bgoff[i] = (bn + brow) * 256 + bkc;
        bloff[i] = brow * HLD + bkc;
    }

    f4_t acc[2] = {};
    bf8_t ra, rb[4];

    if (aval) ra = *(const bf8_t*)(&A[agoff]);
#pragma unroll
    for (int i = 0; i < 4; ++i)
        rb[i] = *(const bf8_t*)(&Bt[bgoff[i]]);

    for (int ks = 0; ks < 8; ++ks) {
        __syncthreads();
        if (aval) *(bf8_t*)(&As[aloff]) = ra;
#pragma unroll
        for (int i = 0; i < 4; ++i)
            *(bf8_t*)(&Bs[bloff[i]]) = rb[i];
        __syncthreads();
        if (ks < 7) {
            int k0 = (ks + 1) * 64;
            int kb = k0 & 255;
            if (aval) ra = *(const bf8_t*)(&A[agoff + k0]);
#pragma unroll
            for (int i = 0; i < 4; ++i)
                rb[i] = *(const bf8_t*)(&Bt[bgoff[i] + kb]);
        }
#pragma unroll
        for (int kk = 0; kk < 2; ++kk) {
            bf8_t af = *(const bf8_t*)(&As[ln * HLD + kk * 32 + quad * 8]);
#pragma unroll
            for (int ni = 0; ni < 2; ++ni) {
                bf8_t bfr = *(const bf8_t*)(&Bs[(wn + ni * 16 + ln) * HLD + kk * 32 + quad * 8]);
                acc[ni] = __builtin_amdgcn_mfma_f32_16x16x32_bf16(af, bfr, acc[ni], 0, 0, 0);
            }
        }
    }

#pragma unroll
    for (int ni = 0; ni < 2; ++ni) {
        int col = bn + wn + ni * 16 + ln;
        float bb = w[F_BCAT + col];
#pragma unroll
        for (int r = 0; r < 4; ++r) {
            int row = bm + quad * 4 + r;
            w[F_HCAT + row * 512 + col] = acc[ni][r] + bb;
        }
    }
}

// Ehat[row] (width 576): [ sum relu(hi_p+hj) hi (256) | deg | 0 | lo (256) | 0 ]
// 1024 blocks, XCD-pinned. Uses precompacted ej lists (no adj read/atomics).
__global__ __launch_bounds__(256) void msg_kernel(float* __restrict__ w)
{
    ushort_t* wb = (ushort_t*)w;
    const float* hcat = w + F_HCAT;
    const int xcd = blockIdx.x & 7;
    const int gph = xcd >> 1;
    const int idx = ((blockIdx.x >> 3) << 1) | (xcd & 1);  // 0..255
    const int row = gph * 256 + idx;
    const int t = threadIdx.x;
    __shared__ ushort_t ejs[256];
    ejs[t] = wb[EJ_U + row * 256 + t];
    const int ne = ((const int*)(w + F_ECNT))[row];
    const float hi = hcat[row * 512 + t];
    const float* hjb = hcat + gph * 256 * 512 + 256;
    __syncthreads();
    float acc = 0.f;
#pragma unroll 4
    for (int p = 0; p < ne; ++p) {
        int j = ejs[p];
        acc += relu(hi + hjb[j * 512 + t]);
    }
    ushort_t h16 = f2b(acc);
    ushort_t l16 = f2b(acc - bf2f(h16));
    ushort_t* er = wb + UB_EHAT2 + row * 576;
    er[t] = h16;
    er[288 + t] = l16;
    if (t < 32) {
        er[256 + t] = f2b(t == 0 ? (float)ne : 0.f);  // deg exact (<=256)
        er[544 + t] = 0;
    }
}

// Fused gi-GEMM + gh-GEMM + GRU.  R14: 512 blocks (8-row slabs, 2/CU),
// XCD-pinned: xcd=bid&7; gph=xcd>>1; lidx 0..127; cg=lidx&3;
// rbase = gph*256 + (lidx>>2)*8.  M-frag stays 16 rows: rows 8..15 are dead
// lanes (A-LDS rows 8..15 uninitialized, outputs discarded via quad<2) ->
// per-output MFMA chain unchanged -> bitwise identical.
// Phase 1: gi = Ehat @ Wg (K=864 dedup, BK=96, 9 rounds).
// Phase 2: gh = h @ Whh (K=512, B=WCATT rows 512..1280 dedup k&255), BK=64.
// h state = H2 hi/lo pairs only; double-buffered rdoff->wroff.
// GRU epilogue register-local. FINAL: last block per graph (counter to 128)
// does readout.
#define GLD 104
template<int FINAL>
__global__ __launch_bounds__(256) void gigru_kernel(float* __restrict__ w,
                                                    void* __restrict__ out,
                                                    int rdoff, int wroff)
{
    __shared__ ushort_t As[16 * GLD];    // 3.3KB (rows 8..15 dead)
    __shared__ ushort_t Bs[192 * GLD];   // 40KB
    __shared__ float gl[256];
    __shared__ float t1[256];
    __shared__ int donef;
    ushort_t* wb = (ushort_t*)w;
    const int t = threadIdx.x;
    const int wave = t >> 6, lane = t & 63;
    const int ln = lane & 15, quad = lane >> 4;
    const int xcd = blockIdx.x & 7;
    const int gph = xcd >> 1;
    const int lidx = ((blockIdx.x >> 3) << 1) | (xcd & 1);   // 0..127
    const int cg = lidx & 3;
    const int rbase = gph * 256 + (lidx >> 2) * 8;

    // ---------------- phase 1: gi = Ehat @ Wg ----------------
    // A slice 8 rows x 96u = 96 chunks (t<96); B 192x96u (9/thread)
    const int aval = (t < 96);
    const int arow = t / 12, akc = (t % 12) * 8;
    const int agoff = (rbase + arow) * 576 + akc;
    const int aloff = arow * GLD + akc;
    int bgoff[9], bloff[9];
#pragma unroll
    for (int i = 0; i < 9; ++i) {
        int slot = i * 256 + t;
        int brow = slot / 12, bkc = (slot % 12) * 8;
        int wrow = (brow >> 6) * 256 + cg * 64 + (brow & 63);
        bgoff[i] = wrow * 576 + bkc;
        bloff[i] = brow * GLD + bkc;
    }
    const ushort_t* Ehp = wb + UB_EHAT2;
    const ushort_t* Bp  = wb + UB_WGT;

    f4_t acc[3] = {};
    {
        bf8_t ra, rb[9];
        if (aval) ra = *(const bf8_t*)(&Ehp[agoff]);
#pragma unroll
        for (int i = 0; i < 9; ++i)
            rb[i] = *(const bf8_t*)(&Bp[bgoff[i]]);

        for (int ks = 0; ks < 9; ++ks) {
            __syncthreads();
            if (aval) *(bf8_t*)(&As[aloff]) = ra;
#pragma unroll
            for (int i = 0; i < 9; ++i)
                *(bf8_t*)(&Bs[bloff[i]]) = rb[i];
            __syncthreads();
            if (ks < 8) {
                int k0 = (ks + 1) * 96;
                int ka = (k0 < 576) ? k0 : k0 - 576;
                int kb = (k0 < 288) ? k0 : k0 - 288;
                if (aval) ra = *(const bf8_t*)(&Ehp[agoff + ka]);
#pragma unroll
                for (int i = 0; i < 9; ++i)
                    rb[i] = *(const bf8_t*)(&Bp[bgoff[i] + kb]);
            }
#pragma unroll
            for (int kk = 0; kk < 3; ++kk) {
                bf8_t af = *(const bf8_t*)(&As[ln * GLD + kk * 32 + quad * 8]);
#pragma unroll
                for (int n = 0; n < 3; ++n) {
                    int fn = wave + n * 4;           // gate n, sub = wave
                    bf8_t bfr = *(const bf8_t*)(&Bs[(fn * 16 + ln) * GLD + kk * 32 + quad * 8]);
                    acc[n] = __builtin_amdgcn_mfma_f32_16x16x32_bf16(af, bfr, acc[n], 0, 0, 0);
                }
            }
        }
    }

    // ---------------- phase 2: gh = h @ Whh ----------------
    // A = h(rdoff) 8 rows x 512; B = WCATT rows 512 + gate*256 + cg*64 + r
    const int aval2 = (t < 64);
    const int arow2 = t >> 3, akc2 = (t & 7) << 3;
    const int agoff2 = (rbase + arow2) * 512 + akc2;
    const int aloff2 = arow2 * GLD + akc2;
    int bgoff2[6], bloff2[6];
#pragma unroll
    for (int i = 0; i < 6; ++i) {
        int slot = i * 256 + t;
        int brow = slot >> 3, bkc = (slot & 7) << 3;
        int wrow = 512 + (brow >> 6) * 256 + cg * 64 + (brow & 63);
        bgoff2[i] = wrow * 256 + bkc;
        bloff2[i] = brow * GLD + bkc;
    }
    const ushort_t* Hp = wb + rdoff;
    const ushort_t* Wp = wb + UB_WCATT;

    f4_t acch[3] = {};
    {
        bf8_t ra, rb[6];
        if (aval2) ra = *(const bf8_t*)(&Hp[agoff2]);
#pragma unroll
        for (int i = 0; i < 6; ++i)
            rb[i] = *(const bf8_t*)(&Wp[bgoff2[i]]);

        for (int ks = 0; ks < 8; ++ks) {
            __syncthreads();
            if (aval2) *(bf8_t*)(&As[aloff2]) = ra;
#pragma unroll
            for (int i = 0; i < 6; ++i)
                *(bf8_t*)(&Bs[bloff2[i]]) = rb[i];
            __syncthreads();
            if (ks < 7) {
                int k0 = (ks + 1) * 64;
                int kb = k0 & 255;
                if (aval2) ra = *(const bf8_t*)(&Hp[agoff2 + k0]);
#pragma unroll
                for (int i = 0; i < 6; ++i)
                    rb[i] = *(const bf8_t*)(&Wp[bgoff2[i] + kb]);
            }
#pragma unroll
            for (int kk = 0; kk < 2; ++kk) {
                bf8_t af = *(const bf8_t*)(&As[ln * GLD + kk * 32 + quad * 8]);
#pragma unroll
                for (int n = 0; n < 3; ++n) {
                    int fn = wave + n * 4;
                    bf8_t bfr = *(const bf8_t*)(&Bs[(fn * 16 + ln) * GLD + kk * 32 + quad * 8]);
                    acch[n] = __builtin_amdgcn_mfma_f32_16x16x32_bf16(af, bfr, acch[n], 0, 0, 0);
                }
            }
        }
    }

    // GRU epilogue: acc=ir/iz/in + bih; acch=hr/hz/hn + bhh.
    // Only quad<2 rows (0..7) are valid for this 8-row slab.
    if (quad < 2) {
        const int col = cg * 64 + wave * 16 + ln;
        float bi_r = w[F_BIH + col];
        float bi_z = w[F_BIH + 256 + col];
        float bi_n = w[F_BIH + 512 + col];
        float bh_r = w[F_BCAT + 512 + col];
        float bh_z = w[F_BCAT + 768 + col];
        float bh_n = w[F_BCAT + 1024 + col];
#pragma unroll
        for (int r = 0; r < 4; ++r) {
            int row = rbase + quad * 4 + r;
            float ir = acc[0][r] + bi_r;
            float iz = acc[1][r] + bi_z;
            float in = acc[2][r] + bi_n;
            float hr = acch[0][r] + bh_r;
            float hz = acch[1][r] + bh_z;
            float hn = acch[2][r] + bh_n;
            float rg_ = 1.f / (1.f + __expf(-(ir + hr)));
            float z   = 1.f / (1.f + __expf(-(iz + hz)));
            float nn  = tanhf(in + rg_ * hn);
            float ho = bf2f(wb[rdoff + row * 512 + col])
                     + bf2f(wb[rdoff + row * 512 + 256 + col]);
            float hv = (1.f - z) * nn + z * ho;
            ushort_t hb = f2b(hv);
            wb[wroff + row * 512 + col] = hb;
            wb[wroff + row * 512 + 256 + col] = f2b(hv - bf2f(hb));
        }
    }

    if (FINAL) {
        // per-graph arrival counter: 128 blocks/graph; last one does readout.
        const int g = gph;
        __syncthreads();
        if (t == 0) {
            __threadfence();                           // release h writes
            int prev = atomicAdd((int*)(w + F_GCNT) + g, 1);
            donef = (prev == 127);
        }
        __syncthreads();
        if (!donef) return;
        __threadfence();                               // acquire others' h

        const ushort_t* h2r = wb + wroff + g * 256 * 512;
        float s = 0.f;
        for (int n = 0; n < 256; ++n)
            s += bf2f(h2r[n * 512 + t]) + bf2f(h2r[n * 512 + 256 + t]);
        gl[t] = s;
        __syncthreads();
        float acc1 = w[F_ROB1 + t];
        for (int k = 0; k < 256; ++k) acc1 += gl[k] * w[F_ROW1 + k * 256 + t];
        t1[t] = relu(acc1);
        __syncthreads();
        if (t < 16) {
            float q = w[F_ROB2 + t];
            for (int k = 0; k < 256; ++k) q += t1[k] * w[F_ROW2 + k * 16 + t];
            if (*(const int*)(w + F_FLAG)) ((float*)out)[g * 16 + t] = q;
            else ((__hip_bfloat16*)out)[g * 16 + t] = __float2bfloat16(q);
        }
    }
}

extern "C" void kernel_launch(void* const* d_in, const int* in_sizes, int n_in,
                              void* d_out, int out_size, void* d_ws, size_t ws_size,
                              hipStream_t stream) {
    float* w = (float*)d_ws;

    static const int dictSz[18]  = {65536,262144,16384,256,65536,256,131072,256,65536,256,
                                    196608,196608,768,768,65536,256,4096,16};
    static const int alphaSz[18] = {262144,196608,196608,768,768,131072,65536,256,256,
                                    65536,16384,65536,256,256,65536,4096,256,16};
    static const int alphaPos[18] = {9,0,10,12,11,13,5,7,6,8,2,1,4,3,14,16,15,17};
    bool dictOK = true, alphaOK = true;
    for (int i = 0; i < 18 && i < n_in; ++i) {
        if (in_sizes[i] != dictSz[i])  dictOK = false;
        if (in_sizes[i] != alphaSz[i]) alphaOK = false;
    }
    const void* P[18];
    for (int l = 0; l < 18; ++l) P[l] = d_in[(!dictOK && alphaOK) ? alphaPos[l] : l];
    const int* adj = (const int*)P[1];

    convwg_kernel<<<NCONV + 216 + 64, 256, 0, stream>>>(
        P[0], P[2], P[3], P[4], P[5], P[6], P[7], P[8], P[9],
        P[10], P[11], P[12], P[13], P[14], P[15], P[16], P[17], adj, w);

    prenet_kernel<<<32, 256, 0, stream>>>(w);

    // h double-buffer: prenet -> A; it0 A->B; it1 B->A; it2 A->B; readout B.
    const int hA = UB_H2, hB = UB_H2B;
    hcat_kernel<<<256, 256, 0, stream>>>(w, hA);
    msg_kernel<<<BN_ROWS, 256, 0, stream>>>(w);
    gigru_kernel<0><<<512, 256, 0, stream>>>(w, d_out, hA, hB);

    hcat_kernel<<<256, 256, 0, stream>>>(w, hB);
    msg_kernel<<<BN_ROWS, 256, 0, stream>>>(w);
    gigru_kernel<0><<<512, 256, 0, stream>>>(w, d_out, hB, hA);

    hcat_kernel<<<256, 256, 0, stream>>>(w, hA);
    msg_kernel<<<BN_ROWS, 256, 0, stream>>>(w);
    gigru_kernel<1><<<512, 256, 0, stream>>>(w, d_out, hA, hB);
}

// Round 15
// 260.080 us; speedup vs baseline: 1.0687x; 1.0687x over previous
//
#include <hip/hip_runtime.h>
#include <hip/hip_bf16.h>

// B=4, N=256, F=64, H=256, A=16, T=3.  BN=1024 rows.
// bf16 inputs (runtime-verified); adjacency int32.
// GEMMs: bf16 MFMA 16x16x32. Weights EXACT in bf16.
// Activations as split hi/lo bf16 pairs along K; weights duplicated along K.
// R1-R13: see history. Best: R11 257.6 / R13 261.8 (within noise).
// R14: 2 blocks/CU TLP -> REGRESSED (59us; conflicts 2x). Reverted.
// Dead theories for gigru's ~47us: volume, rounds, CU-count, conflicts,
// epilogue, XCD-RAW, load-count-per-window, footprint, TLP.
// Surviving model: total ~= sum(per-dispatch cold L2-fill)/150GB/s; each
// round's loads have only 1 round's compute (~300cy) to land (distance-1).
// R15: R13 config + prefetch DISTANCE 2 in gigru (both phases): double reg
// sets, each load gets ~2 rounds to land. Load order only -> bitwise same.
// Pre-commit: null => structure at measured floor; stop.

typedef unsigned short ushort_t;
typedef short bf8_t __attribute__((ext_vector_type(8)));
typedef float f4_t  __attribute__((ext_vector_type(4)));

#define BN_ROWS 1024

// ---- bf16 regions (USHORT offsets) ----
#define UB_NFB    0         // 65536   NF [1024][64] (exact)
#define UB_PW1T   65536     // 16384   preW1^T [256][64]
#define UB_PW2T   81920     // 65536   preW2^T [256][256]
#define UB_WCATT  147456    // 327680  Wcat^T [1280][256] (dedup: k&255)
#define UB_WGT    475136    // 442368  Wg^T [768][576] = [hi(288)|lo(288)]
#define UB_H2     917504    // 524288  h buf A [1024][512] hi|lo
#define UB_EHAT2  1441792   // 589824  Ehat [1024][576] = [Eh(288)|El(288)]
// ushort end 2031616 = float 1015808

// ---- fp32 regions (FLOAT offsets) ----
#define F_PREB1   1015808   // 256
#define F_PREB2   1016064   // 256
#define F_BCAT    1016320   // 1280  [msg_b1 | 0 | gru_bhh]
#define F_BIH     1017600   // 768
#define F_ROW1    1018368   // 65536
#define F_ROB1    1083904   // 256
#define F_ROW2    1084160   // 4096
#define F_ROB2    1088256   // 16
// old F_H region [1088272, 1350416) reused:
#define EJ_U      2176544   // ushort offset (= 1088272*2): ej [1024][256] ushort
#define F_ECNT    1219344   // 1024 ints: per-row edge counts
#define F_HCAT    1350416   // 524288 [hi_p | hj] fp32
// gap [1874704, 2661136) floats reused:
#define UB_H2B    3749408   // ushort offset (= 1874704*2): h buf B [1024][512]
#define F_FLAG    2661136   // 1 int
#define F_GCNT    2661140   // 4 ints: per-graph readout arrival counters

// ---- convert index space ----
#define CVa 65536     // end NFB
#define CVb 81920     // end PW1T
#define CVc 147456    // end PW2T
#define CVd 475136    // end WCATT (1280*256)
#define CV_TOTAL 547600   // + 72464 fp32 tail
#define NCONV 1070        // convert blocks; then 216 wg blocks; then 64 compact

__device__ __forceinline__ float bf2f(ushort_t u) {
    return __uint_as_float(((unsigned int)u) << 16);
}
__device__ __forceinline__ ushort_t f2b(float v) {
    __hip_bfloat16 b = __float2bfloat16(v);
    return *reinterpret_cast<ushort_t*>(&b);
}
__device__ __forceinline__ float relu(float v) { return v < 0.f ? 0.f : v; }  // NaN-propagating
__device__ __forceinline__ float ld(const void* p, int i, int isf32) {
    return isf32 ? ((const float*)p)[i] : bf2f(((const ushort_t*)p)[i]);
}

// detect + convert [0,NCONV) + wg [NCONV,NCONV+216) + adj-compact [+216,+280).
__global__ __launch_bounds__(256) void convwg_kernel(
    const void* nf, const void* preW1, const void* preb1, const void* preW2, const void* preb2,
    const void* msgW1, const void* msgb1, const void* msgW2, const void* msgb2,
    const void* gruWih, const void* gruWhh, const void* grubih, const void* grubhh,
    const void* roW1, const void* rob1, const void* roW2, const void* rob2,
    const int* __restrict__ adj, float* __restrict__ w)
{
    __shared__ float w2s[4 * 256];
    __shared__ int cnt;
    __shared__ int cnt2;
    const int t = threadIdx.x;
    ushort_t* wb = (ushort_t*)w;

    // ---- inline detect (redundant per block; 4KB L2-hit scan) ----
    if (t == 0) cnt = 0;
    __syncthreads();
    {
        const ushort_t* nf0 = (const ushort_t*)nf;
        int bad = 0;
        for (int i = 0; i < 8; ++i) {
            ushort_t u = nf0[(t * 8 + i) * 2];
            int ex = (u >> 7) & 0xFF;
            if ((u & 0x7fff) != 0 && (ex < 100 || ex > 140)) bad++;
        }
        atomicAdd(&cnt, bad);
    }
    __syncthreads();
    const int f32 = (cnt > 512) ? 1 : 0;

    if (blockIdx.x == 0) {          // publish flag + zero readout counters
        if (t < 4) ((int*)(w + F_GCNT))[t] = 0;
        if (t == 4) *(int*)(w + F_FLAG) = f32;
    }

    if (blockIdx.x < NCONV) {
        const int e0 = (blockIdx.x * 256 + t) * 2;
#pragma unroll
        for (int u2 = 0; u2 < 2; ++u2) {
            int e = e0 + u2;
            if (e >= CV_TOTAL) break;
            if (e < CVa) {                                    // NF
                wb[UB_NFB + e] = f2b(ld(nf, e, f32));
            } else if (e < CVb) {                             // preW1^T [256][64]
                int i = e - CVa; int n = i >> 6, k = i & 63;
                wb[UB_PW1T + i] = f2b(ld(preW1, k * 256 + n, f32));
            } else if (e < CVc) {                             // preW2^T [256][256]
                int i = e - CVb; int n = i >> 8, k = i & 255;
                wb[UB_PW2T + i] = f2b(ld(preW2, k * 256 + n, f32));
            } else if (e < CVd) {                             // Wcat^T [1280][256]
                int i = e - CVc; int n = i >> 8, k = i & 255;
                float v;
                if (n < 256)      v = ld(msgW1, k * 256 + n, f32);
                else if (n < 512) v = ld(msgW1, (256 + k) * 256 + (n - 256), f32);
                else              v = ld(gruWhh, k * 768 + (n - 512), f32);
                wb[UB_WCATT + i] = f2b(v);
            } else {                                          // fp32 tail
                int f = e - CVd;
                float v;
                if (f < 256)        v = ld(preb1, f, f32);
                else if (f < 512)   v = ld(preb2, f - 256, f32);
                else if (f < 1792) {
                    int c = f - 512;
                    if (c < 256)      v = ld(msgb1, c, f32);
                    else if (c < 512) v = 0.f;
                    else              v = ld(grubhh, c - 512, f32);
                }
                else if (f < 2560)  v = ld(grubih, f - 1792, f32);
                else if (f < 68096) v = ld(roW1, f - 2560, f32);
                else if (f < 68352) v = ld(rob1, f - 68096, f32);
                else if (f < 72448) v = ld(roW2, f - 68352, f32);
                else                v = ld(rob2, f - 72448, f32);
                w[F_PREB1 + f] = v;
            }
        }
        return;
    }

    if (blockIdx.x < NCONV + 216) {
        // ---- wg path: Wg[k][p] = sum_n W2hat[k][n]*Wih[n][p] -> WgT[p][576] ----
        const int wt = blockIdx.x - NCONV;   // [0,216)
        const int p0 = (wt % 3) * 256;
        const int k0 = (wt / 3) * 4;
        for (int i = t; i < 4 * 256; i += 256) {
            int r = i >> 8, n = i & 255;
            int krow = k0 + r;
            float v;
            if (krow < 256)       v = ld(msgW2, krow * 256 + n, f32);
            else if (krow == 256) v = ld(msgb2, n, f32);
            else                  v = 0.f;
            w2s[i] = v;
        }
        __syncthreads();
        const int p = p0 + t;
        float acc4[4] = {};
        for (int n0 = 0; n0 < 256; n0 += 32) {
            float wv[32];
#pragma unroll
            for (int i = 0; i < 32; ++i)
                wv[i] = ld(gruWih, (n0 + i) * 768 + p, f32);
#pragma unroll
            for (int r = 0; r < 4; ++r) {
                float acc = acc4[r];
#pragma unroll
                for (int q = 0; q < 8; ++q) {
                    f4_t w4 = *(const f4_t*)&w2s[r * 256 + n0 + q * 4];
                    acc += w4[0] * wv[q * 4 + 0] + w4[1] * wv[q * 4 + 1]
                         + w4[2] * wv[q * 4 + 2] + w4[3] * wv[q * 4 + 3];
                }
                acc4[r] = acc;
            }
        }
#pragma unroll
        for (int r = 0; r < 4; ++r) {
            int krow = k0 + r;
            ushort_t hi = f2b(acc4[r]);
            ushort_t lo = f2b(acc4[r] - bf2f(hi));
            wb[UB_WGT + p * 576 + krow] = hi;
            wb[UB_WGT + p * 576 + 288 + krow] = lo;
        }
        return;
    }

    // ---- adjacency compaction: 64 blocks x 16 rows -> ej lists + counts ----
    {
        const int r0 = (blockIdx.x - (NCONV + 216)) * 16;
        for (int i = 0; i < 16; ++i) {
            const int row = r0 + i;
            __syncthreads();
            if (t == 0) cnt2 = 0;
            __syncthreads();
            if (adj[row * 256 + t]) {
                int p = atomicAdd(&cnt2, 1);
                wb[EJ_U + row * 256 + p] = (ushort_t)t;
            }
            __syncthreads();
            if (t == 0) ((int*)(w + F_ECNT))[row] = cnt2;
        }
    }
}

// Fused pre-net: X = relu(NF@preW1+b1) (in LDS), h = X@preW2+b2 -> H2 (buf A).
// 32 blocks x 32 rows, XCD-pinned: graph g on XCDs {2g,2g+1}.
__global__ __launch_bounds__(256) void prenet_kernel(float* __restrict__ w)
{
    __shared__ ushort_t As[32 * 64];    // NF tile      4KB
    __shared__ ushort_t Xs[32 * 256];   // X tile      16KB
    __shared__ ushort_t Bs[256 * 32];   // weight slab 16KB
    ushort_t* wb = (ushort_t*)w;
    const int t = threadIdx.x;
    const int wave = t >> 6, lane = t & 63;
    const int ln = lane & 15, quad = lane >> 4;
    const int wr = (wave & 1) * 16, wc = (wave >> 1) * 128;
    const int xcd = blockIdx.x & 7;
    const int gph = xcd >> 1;
    const int lidx = ((blockIdx.x >> 3) << 1) | (xcd & 1);   // 0..7
    const int rbase = gph * 256 + lidx * 32;
    const int srow = t >> 2, skc = (t & 3) << 3;

    // stage NF tile [32][64]: 1 bf8 per thread
    {
        int row = t >> 3, kc = (t & 7) << 3;
        *(bf8_t*)(&As[row * 64 + kc]) =
            *(const bf8_t*)(&wb[UB_NFB + (rbase + row) * 64 + kc]);
    }

    f4_t acc[8] = {};
    // phase A: X = relu(NF @ PW1T + b1), K=64
    for (int k0 = 0; k0 < 64; k0 += 32) {
        __syncthreads();
#pragma unroll
        for (int rr = 0; rr < 4; ++rr) {
            int n = srow + 64 * rr;
            *(bf8_t*)(&Bs[n * 32 + skc]) =
                *(const bf8_t*)(&wb[UB_PW1T + n * 64 + k0 + skc]);
        }
        __syncthreads();
        bf8_t af = *(const bf8_t*)(&As[(wr + ln) * 64 + k0 + quad * 8]);
#pragma unroll
        for (int n = 0; n < 8; ++n) {
            bf8_t bfr = *(const bf8_t*)(&Bs[(wc + n * 16 + ln) * 32 + quad * 8]);
            acc[n] = __builtin_amdgcn_mfma_f32_16x16x32_bf16(af, bfr, acc[n], 0, 0, 0);
        }
    }
    __syncthreads();
#pragma unroll
    for (int n = 0; n < 8; ++n) {
        int col = wc + n * 16 + ln;
        float bb = w[F_PREB1 + col];
#pragma unroll
        for (int r = 0; r < 4; ++r) {
            int row = wr + quad * 4 + r;
            Xs[row * 256 + col] = f2b(relu(acc[n][r] + bb));
        }
        acc[n] = (f4_t){0.f, 0.f, 0.f, 0.f};
    }
    __syncthreads();

    // phase B: h = X @ PW2T + b2, K=256
    for (int k0 = 0; k0 < 256; k0 += 32) {
        __syncthreads();
#pragma unroll
        for (int rr = 0; rr < 4; ++rr) {
            int n = srow + 64 * rr;
            *(bf8_t*)(&Bs[n * 32 + skc]) =
                *(const bf8_t*)(&wb[UB_PW2T + n * 256 + k0 + skc]);
        }
        __syncthreads();
        bf8_t af = *(const bf8_t*)(&Xs[(wr + ln) * 256 + k0 + quad * 8]);
#pragma unroll
        for (int n = 0; n < 8; ++n) {
            bf8_t bfr = *(const bf8_t*)(&Bs[(wc + n * 16 + ln) * 32 + quad * 8]);
            acc[n] = __builtin_amdgcn_mfma_f32_16x16x32_bf16(af, bfr, acc[n], 0, 0, 0);
        }
    }
#pragma unroll
    for (int n = 0; n < 8; ++n) {
        int col = wc + n * 16 + ln;
        float bb = w[F_PREB2 + col];
#pragma unroll
        for (int r = 0; r < 4; ++r) {
            int grow = rbase + wr + quad * 4 + r;
            float v = acc[n][r] + bb;
            ushort_t hi = f2b(v);
            wb[UB_H2 + grow * 512 + col] = hi;
            wb[UB_H2 + grow * 512 + 256 + col] = f2b(v - bf2f(hi));
        }
    }
}

// hcat GEMM: C[1024,512] = h[1024,512] @ WcatT[0..512]^T + bias ([hi_p|hj]).
// 32x128 tiles, 128 blocks, XCD-pinned. BK=64, LDS stride 104u, prefetch 1.
#define HLD 104
__global__ __launch_bounds__(256) void hcat_kernel(float* __restrict__ w, int hoff)
{
    __shared__ ushort_t As[32 * HLD];    // 6.6KB
    __shared__ ushort_t Bs[128 * HLD];   // 26.6KB
    ushort_t* wb = (ushort_t*)w;
    const ushort_t* A  = wb + hoff;
    const ushort_t* Bt = wb + UB_WCATT;
    const int t = threadIdx.x;
    const int wave = t >> 6, lane = t & 63;
    const int ln = lane & 15, quad = lane >> 4;
    const int xcd = blockIdx.x & 7;
    const int gph = xcd >> 1;
    const int lidx = ((blockIdx.x >> 3) << 1) | (xcd & 1);   // 0..31
    const int bm = gph * 256 + (lidx >> 2) * 32;
    const int bn = (lidx & 3) * 128;
    const int wm = (wave >> 1) * 16, wn = (wave & 1) * 64;

    const int arow = t >> 3, akc = (t & 7) << 3;
    const int agoff = (bm + arow) * 512 + akc;
    const int aloff = arow * HLD + akc;
    int bgoff[4], bloff[4];
#pragma unroll
    for (int i = 0; i < 4; ++i) {
        int slot = i * 256 + t;
        int brow = slot >> 3, bkc = (slot & 7) << 3;
        bgoff[i] = (bn + brow) * 256 + bkc;
        bloff[i] = brow * HLD + bkc;
    }

    f4_t acc[4] = {};
    bf8_t ra, rb[4];

    ra = *(const bf8_t*)(&A[agoff]);
#pragma unroll
    for (int i = 0; i < 4; ++i)
        rb[i] = *(const bf8_t*)(&Bt[bgoff[i]]);

    for (int ks = 0; ks < 8; ++ks) {
        __syncthreads();
        *(bf8_t*)(&As[aloff]) = ra;
#pragma unroll
        for (int i = 0; i < 4; ++i)
            *(bf8_t*)(&Bs[bloff[i]]) = rb[i];
        __syncthreads();
        if (ks < 7) {
            int k0 = (ks + 1) * 64;
            int kb = k0 & 255;
            ra = *(const bf8_t*)(&A[agoff + k0]);
#pragma unroll
            for (int i = 0; i < 4; ++i)
                rb[i] = *(const bf8_t*)(&Bt[bgoff[i] + kb]);
        }
#pragma unroll
        for (int kk = 0; kk < 2; ++kk) {
            bf8_t af = *(const bf8_t*)(&As[(wm + ln) * HLD + kk * 32 + quad * 8]);
#pragma unroll
            for (int ni = 0; ni < 4; ++ni) {
                bf8_t bfr = *(const bf8_t*)(&Bs[(wn + ni * 16 + ln) * HLD + kk * 32 + quad * 8]);
                acc[ni] = __builtin_amdgcn_mfma_f32_16x16x32_bf16(af, bfr, acc[ni], 0, 0, 0);
            }
        }
    }

#pragma unroll
    for (int ni = 0; ni < 4; ++ni) {
        int col = bn + wn + ni * 16 + ln;
        float bb = w[F_BCAT + col];
#pragma unroll
        for (int r = 0; r < 4; ++r) {
            int row = bm + wm + quad * 4 + r;
            w[F_HCAT + row * 512 + col] = acc[ni][r] + bb;
        }
    }
}

// Ehat[row] (width 576): [ sum relu(hi_p+hj) hi (256) | deg | 0 | lo (256) | 0 ]
// 1024 blocks, XCD-pinned. Uses precompacted ej lists (no adj read/atomics).
__global__ __launch_bounds__(256) void msg_kernel(float* __restrict__ w)
{
    ushort_t* wb = (ushort_t*)w;
    const float* hcat = w + F_HCAT;
    const int xcd = blockIdx.x & 7;
    const int gph = xcd >> 1;
    const int idx = ((blockIdx.x >> 3) << 1) | (xcd & 1);  // 0..255
    const int row = gph * 256 + idx;
    const int t = threadIdx.x;
    __shared__ ushort_t ejs[256];
    ejs[t] = wb[EJ_U + row * 256 + t];
    const int ne = ((const int*)(w + F_ECNT))[row];
    const float hi = hcat[row * 512 + t];
    const float* hjb = hcat + gph * 256 * 512 + 256;
    __syncthreads();
    float acc = 0.f;
#pragma unroll 4
    for (int p = 0; p < ne; ++p) {
        int j = ejs[p];
        acc += relu(hi + hjb[j * 512 + t]);
    }
    ushort_t h16 = f2b(acc);
    ushort_t l16 = f2b(acc - bf2f(h16));
    ushort_t* er = wb + UB_EHAT2 + row * 576;
    er[t] = h16;
    er[288 + t] = l16;
    if (t < 32) {
        er[256 + t] = f2b(t == 0 ? (float)ne : 0.f);  // deg exact (<=256)
        er[544 + t] = 0;
    }
}

// Fused gi-GEMM + gh-GEMM + GRU.  256 blocks, XCD-pinned (R11 map).
// R15: prefetch DISTANCE 2 (double register sets) in both phases; load order
// only -> MFMA chains unchanged -> bitwise identical to R13.
// Phase 1: gi = Ehat @ Wg (K=864 dedup, BK=96, 9 rounds).
// Phase 2: gh = h @ Whh (K=512, B=WCATT rows 512..1280 dedup k&255), BK=64.
// h state = H2 hi/lo pairs only; double-buffered rdoff->wroff.
// GRU epilogue register-local. FINAL: last block per graph does readout.
#define GLD 104
template<int FINAL>
__global__ __launch_bounds__(256) void gigru_kernel(float* __restrict__ w,
                                                    void* __restrict__ out,
                                                    int rdoff, int wroff)
{
    __shared__ ushort_t As[16 * GLD];    // 3.3KB
    __shared__ ushort_t Bs[192 * GLD];   // 40KB
    __shared__ float gl[256];
    __shared__ float t1[256];
    __shared__ int donef;
    ushort_t* wb = (ushort_t*)w;
    const int t = threadIdx.x;
    const int wave = t >> 6, lane = t & 63;
    const int ln = lane & 15, quad = lane >> 4;
    const int xcd = blockIdx.x & 7;
    const int gph = xcd >> 1;
    const int lidx = ((blockIdx.x >> 3) << 1) | (xcd & 1);   // 0..63
    const int cg = lidx & 3;
    const int rg = gph * 16 + (lidx >> 2);                   // 0..63
    const int rbase = rg * 16;

    // ---------------- phase 1: gi = Ehat @ Wg (distance-2 prefetch) --------
    const int aval = (t < 192);
    const int arow = t / 12, akc = (t % 12) * 8;
    const int agoff = (rbase + arow) * 576 + akc;
    const int aloff = arow * GLD + akc;
    int bgoff[9], bloff[9];
#pragma unroll
    for (int i = 0; i < 9; ++i) {
        int slot = i * 256 + t;
        int brow = slot / 12, bkc = (slot % 12) * 8;
        int wrow = (brow >> 6) * 256 + cg * 64 + (brow & 63);
        bgoff[i] = wrow * 576 + bkc;
        bloff[i] = brow * GLD + bkc;
    }
    const ushort_t* Ehp = wb + UB_EHAT2;
    const ushort_t* Bp  = wb + UB_WGT;

    f4_t acc[3] = {};
    {
        bf8_t ra[2], rb[2][9];
        // preload rounds 0 and 1 (k remap: A k<576 else k-576; B k<288 else k-288)
        if (aval) ra[0] = *(const bf8_t*)(&Ehp[agoff]);
#pragma unroll
        for (int i = 0; i < 9; ++i)
            rb[0][i] = *(const bf8_t*)(&Bp[bgoff[i]]);
        if (aval) ra[1] = *(const bf8_t*)(&Ehp[agoff + 96]);
#pragma unroll
        for (int i = 0; i < 9; ++i)
            rb[1][i] = *(const bf8_t*)(&Bp[bgoff[i] + 96]);

        for (int ks = 0; ks < 9; ++ks) {
            const int cur = ks & 1;
            __syncthreads();
            if (aval) *(bf8_t*)(&As[aloff]) = ra[cur];
#pragma unroll
            for (int i = 0; i < 9; ++i)
                *(bf8_t*)(&Bs[bloff[i]]) = rb[cur][i];
            __syncthreads();
            if (ks < 7) {
                int k0 = (ks + 2) * 96;
                int ka = (k0 < 576) ? k0 : k0 - 576;
                int kb = (k0 < 288) ? k0 : k0 - 288;
                if (aval) ra[cur] = *(const bf8_t*)(&Ehp[agoff + ka]);
#pragma unroll
                for (int i = 0; i < 9; ++i)
                    rb[cur][i] = *(const bf8_t*)(&Bp[bgoff[i] + kb]);
            }
#pragma unroll
            for (int kk = 0; kk < 3; ++kk) {
                bf8_t af = *(const bf8_t*)(&As[ln * GLD + kk * 32 + quad * 8]);
#pragma unroll
                for (int n = 0; n < 3; ++n) {
                    int fn = wave + n * 4;           // gate n, sub = wave
                    bf8_t bfr = *(const bf8_t*)(&Bs[(fn * 16 + ln) * GLD + kk * 32 + quad * 8]);
                    acc[n] = __builtin_amdgcn_mfma_f32_16x16x32_bf16(af, bfr, acc[n], 0, 0, 0);
                }
            }
        }
    }

    // ---------------- phase 2: gh = h @ Whh (distance-2 prefetch) ----------
    // A = h(rdoff) [16][512]; B = WCATT rows 512 + gate*256 + cg*64 + r
    const int aval2 = (t < 128);
    const int arow2 = t >> 3, akc2 = (t & 7) << 3;
    const int agoff2 = (rbase + arow2) * 512 + akc2;
    const int aloff2 = arow2 * GLD + akc2;
    int bgoff2[6], bloff2[6];
#pragma unroll
    for (int i = 0; i < 6; ++i) {
        int slot = i * 256 + t;
        int brow = slot >> 3, bkc = (slot & 7) << 3;
        int wrow = 512 + (brow >> 6) * 256 + cg * 64 + (brow & 63);
        bgoff2[i] = wrow * 256 + bkc;
        bloff2[i] = brow * GLD + bkc;
    }
    const ushort_t* Hp = wb + rdoff;
    const ushort_t* Wp = wb + UB_WCATT;

    f4_t acch[3] = {};
    {
        bf8_t ra[2], rb[2][6];
        if (aval2) ra[0] = *(const bf8_t*)(&Hp[agoff2]);
#pragma unroll
        for (int i = 0; i < 6; ++i)
            rb[0][i] = *(const bf8_t*)(&Wp[bgoff2[i]]);
        if (aval2) ra[1] = *(const bf8_t*)(&Hp[agoff2 + 64]);
#pragma unroll
        for (int i = 0; i < 6; ++i)
            rb[1][i] = *(const bf8_t*)(&Wp[bgoff2[i] + 64]);

        for (int ks = 0; ks < 8; ++ks) {
            const int cur = ks & 1;
            __syncthreads();
            if (aval2) *(bf8_t*)(&As[aloff2]) = ra[cur];
#pragma unroll
            for (int i = 0; i < 6; ++i)
                *(bf8_t*)(&Bs[bloff2[i]]) = rb[cur][i];
            __syncthreads();
            if (ks < 6) {
                int k0 = (ks + 2) * 64;
                int kb = k0 & 255;
                if (aval2) ra[cur] = *(const bf8_t*)(&Hp[agoff2 + k0]);
#pragma unroll
                for (int i = 0; i < 6; ++i)
                    rb[cur][i] = *(const bf8_t*)(&Wp[bgoff2[i] + kb]);
            }
#pragma unroll
            for (int kk = 0; kk < 2; ++kk) {
                bf8_t af = *(const bf8_t*)(&As[ln * GLD + kk * 32 + quad * 8]);
#pragma unroll
                for (int n = 0; n < 3; ++n) {
                    int fn = wave + n * 4;
                    bf8_t bfr = *(const bf8_t*)(&Bs[(fn * 16 + ln) * GLD + kk * 32 + quad * 8]);
                    acch[n] = __builtin_amdgcn_mfma_f32_16x16x32_bf16(af, bfr, acch[n], 0, 0, 0);
                }
            }
        }
    }

    // GRU epilogue: acc=ir/iz/in + bih; acch=hr/hz/hn + bhh.
    // ho reconstructed from rdoff hi/lo pair; new h written to wroff.
    {
        const int col = cg * 64 + wave * 16 + ln;
        float bi_r = w[F_BIH + col];
        float bi_z = w[F_BIH + 256 + col];
        float bi_n = w[F_BIH + 512 + col];
        float bh_r = w[F_BCAT + 512 + col];
        float bh_z = w[F_BCAT + 768 + col];
        float bh_n = w[F_BCAT + 1024 + col];
#pragma unroll
        for (int r = 0; r < 4; ++r) {
            int row = rbase + quad * 4 + r;
            float ir = acc[0][r] + bi_r;
            float iz = acc[1][r] + bi_z;
            float in = acc[2][r] + bi_n;
            float hr = acch[0][r] + bh_r;
            float hz = acch[1][r] + bh_z;
            float hn = acch[2][r] + bh_n;
            float rg_ = 1.f / (1.f + __expf(-(ir + hr)));
            float z   = 1.f / (1.f + __expf(-(iz + hz)));
            float nn  = tanhf(in + rg_ * hn);
            float ho = bf2f(wb[rdoff + row * 512 + col])
                     + bf2f(wb[rdoff + row * 512 + 256 + col]);
            float hv = (1.f - z) * nn + z * ho;
            ushort_t hb = f2b(hv);
            wb[wroff + row * 512 + col] = hb;
            wb[wroff + row * 512 + 256 + col] = f2b(hv - bf2f(hb));
        }
    }

    if (FINAL) {
        // per-graph arrival counter: 64 blocks/graph; last one does readout.
        const int g = gph;
        __syncthreads();
        if (t == 0) {
            __threadfence();                           // release h writes
            int prev = atomicAdd((int*)(w + F_GCNT) + g, 1);
            donef = (prev == 63);
        }
        __syncthreads();
        if (!donef) return;
        __threadfence();                               // acquire others' h

        const ushort_t* h2r = wb + wroff + g * 256 * 512;
        float s = 0.f;
        for (int n = 0; n < 256; ++n)
            s += bf2f(h2r[n * 512 + t]) + bf2f(h2r[n * 512 + 256 + t]);
        gl[t] = s;
        __syncthreads();
        float acc1 = w[F_ROB1 + t];
        for (int k = 0; k < 256; ++k) acc1 += gl[k] * w[F_ROW1 + k * 256 + t];
        t1[t] = relu(acc1);
        __syncthreads();
        if (t < 16) {
            float q = w[F_ROB2 + t];
            for (int k = 0; k < 256; ++k) q += t1[k] * w[F_ROW2 + k * 16 + t];
            if (*(const int*)(w + F_FLAG)) ((float*)out)[g * 16 + t] = q;
            else ((__hip_bfloat16*)out)[g * 16 + t] = __float2bfloat16(q);
        }
    }
}

extern "C" void kernel_launch(void* const* d_in, const int* in_sizes, int n_in,
                              void* d_out, int out_size, void* d_ws, size_t ws_size,
                              hipStream_t stream) {
    float* w = (float*)d_ws;

    static const int dictSz[18]  = {65536,262144,16384,256,65536,256,131072,256,65536,256,
                                    196608,196608,768,768,65536,256,4096,16};
    static const int alphaSz[18] = {262144,196608,196608,768,768,131072,65536,256,256,
                                    65536,16384,65536,256,256,65536,4096,256,16};
    static const int alphaPos[18] = {9,0,10,12,11,13,5,7,6,8,2,1,4,3,14,16,15,17};
    bool dictOK = true, alphaOK = true;
    for (int i = 0; i < 18 && i < n_in; ++i) {
        if (in_sizes[i] != dictSz[i])  dictOK = false;
        if (in_sizes[i] != alphaSz[i]) alphaOK = false;
    }
    const void* P[18];
    for (int l = 0; l < 18; ++l) P[l] = d_in[(!dictOK && alphaOK) ? alphaPos[l] : l];
    const int* adj = (const int*)P[1];

    convwg_kernel<<<NCONV + 216 + 64, 256, 0, stream>>>(
        P[0], P[2], P[3], P[4], P[5], P[6], P[7], P[8], P[9],
        P[10], P[11], P[12], P[13], P[14], P[15], P[16], P[17], adj, w);

    prenet_kernel<<<32, 256, 0, stream>>>(w);

    // h double-buffer: prenet -> A; it0 A->B; it1 B->A; it2 A->B; readout B.
    const int hA = UB_H2, hB = UB_H2B;
    hcat_kernel<<<128, 256, 0, stream>>>(w, hA);
    msg_kernel<<<BN_ROWS, 256, 0, stream>>>(w);
    gigru_kernel<0><<<256, 256, 0, stream>>>(w, d_out, hA, hB);

    hcat_kernel<<<128, 256, 0, stream>>>(w, hB);
    msg_kernel<<<BN_ROWS, 256, 0, stream>>>(w);
    gigru_kernel<0><<<256, 256, 0, stream>>>(w, d_out, hB, hA);

    hcat_kernel<<<128, 256, 0, stream>>>(w, hA);
    msg_kernel<<<BN_ROWS, 256, 0, stream>>>(w);
    gigru_kernel<1><<<256, 256, 0, stream>>>(w, d_out, hA, hB);
}